// Round 3
// baseline (73219.971 us; speedup 1.0000x reference)
//
#include <hip/hip_runtime.h>
#include <cstdint>

#define T_STEPS 8192
#define HDIM    768
#define G3      2304   // 3*H
#define NDR     4608   // 2*3*H
#define HC      1536   // 2*H
#define GPD     96     // workgroups per direction
#define C_ROWS  8      // h-rows per workgroup (2 per wave)
#define NSLOT   192    // 2 dirs x 96 slots
#define CLAIM_GRID 1024

// ---------------------------------------------------------------------------
// GEMM: C[m][n] = sum_k X[m][k] * W[n][k] + bias[n]  (unchanged)
// ---------------------------------------------------------------------------
__global__ __launch_bounds__(256)
void gemm_xwt(const float* __restrict__ X, const float* __restrict__ W,
              const float* __restrict__ bias, float* __restrict__ C,
              int M, int N, int K) {
    __shared__ float As[16][132];
    __shared__ float Bs[16][132];
    const int tid = threadIdx.x;
    const int m0 = blockIdx.y * 128;
    const int n0 = blockIdx.x * 128;
    const int tm = tid >> 4;
    const int tn = tid & 15;
    float acc[8][8] = {};
    for (int k0 = 0; k0 < K; k0 += 16) {
        #pragma unroll
        for (int l = 0; l < 2; ++l) {
            int idx = l * 256 + tid;
            int row = idx >> 2;
            int kc  = (idx & 3) << 2;
            float4 a = *(const float4*)(X + (size_t)(m0 + row) * K + k0 + kc);
            As[kc + 0][row] = a.x; As[kc + 1][row] = a.y;
            As[kc + 2][row] = a.z; As[kc + 3][row] = a.w;
            float4 b = *(const float4*)(W + (size_t)(n0 + row) * K + k0 + kc);
            Bs[kc + 0][row] = b.x; Bs[kc + 1][row] = b.y;
            Bs[kc + 2][row] = b.z; Bs[kc + 3][row] = b.w;
        }
        __syncthreads();
        #pragma unroll
        for (int k = 0; k < 16; ++k) {
            float4 a0 = *(const float4*)&As[k][tm * 8];
            float4 a1 = *(const float4*)&As[k][tm * 8 + 4];
            float4 b0 = *(const float4*)&Bs[k][tn * 8];
            float4 b1 = *(const float4*)&Bs[k][tn * 8 + 4];
            float av[8] = {a0.x, a0.y, a0.z, a0.w, a1.x, a1.y, a1.z, a1.w};
            float bv[8] = {b0.x, b0.y, b0.z, b0.w, b1.x, b1.y, b1.z, b1.w};
            #pragma unroll
            for (int i = 0; i < 8; ++i)
                #pragma unroll
                for (int j = 0; j < 8; ++j)
                    acc[i][j] = fmaf(av[i], bv[j], acc[i][j]);
        }
        __syncthreads();
    }
    float bfrag[8];
    #pragma unroll
    for (int j = 0; j < 8; ++j) bfrag[j] = bias[n0 + tn * 8 + j];
    #pragma unroll
    for (int i = 0; i < 8; ++i) {
        float* cp = C + (size_t)(m0 + tm * 8 + i) * N + n0 + tn * 8;
        float4 o0, o1;
        o0.x = acc[i][0] + bfrag[0]; o0.y = acc[i][1] + bfrag[1];
        o0.z = acc[i][2] + bfrag[2]; o0.w = acc[i][3] + bfrag[3];
        o1.x = acc[i][4] + bfrag[4]; o1.y = acc[i][5] + bfrag[5];
        o1.z = acc[i][6] + bfrag[6]; o1.w = acc[i][7] + bfrag[7];
        *(float4*)(cp + 0) = o0;
        *(float4*)(cp + 4) = o1;
    }
}

// ---------------------------------------------------------------------------
// GRU recurrence, R12 = R9 body (proven) + three fail-safe changes:
// 1) COALESCED poll: lane tid owns pairs {tid+96k}, so a wave-load touches
//    8 L2 lines, not 64 (R9's lane-owns-contiguous-64B was stride-64B across
//    lanes = 64 lines/instr = fabric request-rate saturation).
// 2) XCD-placement claims (CAS slot table; primaries by XCC_ID on XCD 0/1,
//    time-delayed fallback sweep guarantees all 192 slots owned regardless
//    of XCC_ID sanity). Publishes stay AGENT-scope atomics (R9-proven,
//    visible to every poll mode). Polls try sc0 (local L2 ~200cy); sticky
//    per-lane escalation to agent loads after 2048 retries. Every spin has
//    a guaranteed exit -> no-hang by construction.
// 3) Gi prefetch for t+1 issued after the poll (its HBM miss no longer sits
//    under the poll's vmcnt(0)); Hout store deferred one phase.
// Dot partition / butterfly / gates / publish protocol identical to R9.
// ---------------------------------------------------------------------------
__device__ __forceinline__ float sigf(float x) {
    return 1.0f / (1.0f + expf(-x));
}
__device__ __forceinline__ unsigned long long ld_pair(
        const unsigned long long* p) {
    return __hip_atomic_load(p, __ATOMIC_RELAXED, __HIP_MEMORY_SCOPE_AGENT);
}
__device__ __forceinline__ void st_pair(unsigned long long* p,
                                        unsigned long long v) {
    __hip_atomic_store(p, v, __ATOMIC_RELAXED, __HIP_MEMORY_SCOPE_AGENT);
}
__device__ __forceinline__ unsigned ld_u32(const unsigned* p) {
    return __hip_atomic_load(p, __ATOMIC_RELAXED, __HIP_MEMORY_SCOPE_AGENT);
}

// 8 sc0 loads (L1-bypass, local-L2 read) issued together, one wait.
__device__ __forceinline__ void poll_fast8(
        const unsigned long long* p0, const unsigned long long* p1,
        const unsigned long long* p2, const unsigned long long* p3,
        const unsigned long long* p4, const unsigned long long* p5,
        const unsigned long long* p6, const unsigned long long* p7,
        unsigned long long* v) {
    asm volatile(
        "global_load_dwordx2 %0, %8, off sc0\n\t"
        "global_load_dwordx2 %1, %9, off sc0\n\t"
        "global_load_dwordx2 %2, %10, off sc0\n\t"
        "global_load_dwordx2 %3, %11, off sc0\n\t"
        "global_load_dwordx2 %4, %12, off sc0\n\t"
        "global_load_dwordx2 %5, %13, off sc0\n\t"
        "global_load_dwordx2 %6, %14, off sc0\n\t"
        "global_load_dwordx2 %7, %15, off sc0\n\t"
        "s_waitcnt vmcnt(0)"
        : "=&v"(v[0]), "=&v"(v[1]), "=&v"(v[2]), "=&v"(v[3]),
          "=&v"(v[4]), "=&v"(v[5]), "=&v"(v[6]), "=&v"(v[7])
        : "v"(p0), "v"(p1), "v"(p2), "v"(p3),
          "v"(p4), "v"(p5), "v"(p6), "v"(p7)
        : "memory");
}

__global__ __launch_bounds__(256, 1)
void gru_rec(const float* __restrict__ Gi,   // [T][2][2304]
             const float* __restrict__ whh,  // [2][2304][768]
             const float* __restrict__ bhh,  // [2][2304]
             const float* __restrict__ h0,   // [2][768] (layer slice)
             unsigned long long* __restrict__ exch, // [2 par][2 dir][768]
             unsigned* __restrict__ slotowner, // [192] CAS claim table
             float* __restrict__ Hout) {     // [T][2][768]
    __shared__ float hsh[2][768];
    __shared__ float gsum[24];
    __shared__ int claim_sh;

    const int tid  = threadIdx.x;
    const int lane = tid & 63;
    const int wave = tid >> 6;

    // --- claim a slot. Primaries: XCD 0 -> dir-0 slots, XCD 1 -> dir-1.
    // Fallback (after ~100us): sweep all 192 -> completeness guaranteed
    // even if XCC_ID is broken. Ownership unique via CAS. Non-owners exit.
    if (tid == 0) {
        int own = -1;
        unsigned xcc;
        asm volatile("s_getreg_b32 %0, hwreg(HW_REG_XCC_ID)" : "=s"(xcc));
        xcc &= 7u;
        if (xcc < 2u) {
            const int s0 = (int)xcc * GPD;
            for (int s = s0; s < s0 + GPD; ++s) {
                if (ld_u32(&slotowner[s]) == 0u &&
                    atomicCAS(&slotowner[s], 0u, 1u) == 0u) { own = s; break; }
            }
        }
        if (own < 0) {
            for (int i = 0; i < 32; ++i) __builtin_amdgcn_s_sleep(127);
            for (int s = 0; s < NSLOT; ++s) {
                if (ld_u32(&slotowner[s]) == 0u &&
                    atomicCAS(&slotowner[s], 0u, 1u) == 0u) { own = s; break; }
            }
        }
        claim_sh = own;
    }
    __syncthreads();
    const int cl = claim_sh;
    if (cl < 0) return;
    const int d  = cl / GPD;
    const int j0 = (cl % GPD) * C_ROWS;

    // Register-resident weights: m = g*2 + ri, row = j0 + wave + 4*ri.
    float4 w[6][3];
    #pragma unroll
    for (int g = 0; g < 3; ++g)
        #pragma unroll
        for (int ri = 0; ri < 2; ++ri) {
            const float* wrow = whh + (size_t)d * G3 * HDIM
                + (size_t)(g * 768 + j0 + wave + 4 * ri) * HDIM;
            #pragma unroll
            for (int i = 0; i < 3; ++i)
                w[g * 2 + ri][i] = *(const float4*)(wrow + i * 256 + lane * 4);
        }

    // Gate lanes (wave 0, tid<8): row = j0 + tid; constants + initial h.
    float bh_r = 0.f, bh_z = 0.f, bh_n = 0.f, hprev = 0.f;
    float gi_r = 0.f, gi_z = 0.f, gi_n = 0.f;
    if (tid < 8) {
        const int row = j0 + tid;
        bh_r  = bhh[d * G3 +        row];
        bh_z  = bhh[d * G3 +  768 + row];
        bh_n  = bhh[d * G3 + 1536 + row];
        hprev = h0[d * 768 + row];
        const float* gp = Gi + (size_t)d * G3;      // t = 0
        gi_r = gp[        j0 + tid];
        gi_z = gp[ 768 + j0 + tid];
        gi_n = gp[1536 + j0 + tid];
    }

    bool fastok = true;  // sticky per-lane: sc0 polls until proven stale

    for (int t = 0; t < T_STEPS; ++t) {
        // --- Phase 1: coalesced poll (96 lanes, pair p = tid + 96k) ---
        if (tid < 96) {
            if (t == 0) {
                const float* src = h0 + d * 768;
                #pragma unroll
                for (int k = 0; k < 8; ++k)
                    hsh[0][96 * k + tid] = src[96 * k + tid];
            } else {
                const unsigned long long* src = exch
                    + (size_t)((((t - 1) & 1) * 2 + d)) * 768 + tid;
                unsigned long long v[8];
                bool ok;
                int it = 0;
                do {
                    if (fastok) {
                        poll_fast8(src, src + 96, src + 192, src + 288,
                                   src + 384, src + 480, src + 576, src + 672,
                                   v);
                    } else {
                        #pragma unroll
                        for (int k = 0; k < 8; ++k)
                            v[k] = ld_pair(src + 96 * k);
                    }
                    ok = true;
                    #pragma unroll
                    for (int k = 0; k < 8; ++k)
                        ok &= ((unsigned)v[k] >= (unsigned)t);
                    if (!ok && fastok && ++it > 2048) fastok = false;
                } while (!ok);
                #pragma unroll
                for (int k = 0; k < 8; ++k)
                    hsh[t & 1][96 * k + tid] =
                        __uint_as_float((unsigned)(v[k] >> 32));
            }
        }
        __syncthreads();

        // --- Phase 2: deferred Hout(t-1), Gi prefetch(t+1), dot+butterfly ---
        float ngr = 0.f, ngz = 0.f, ngn = 0.f;
        if (tid < 8) {
            if (t > 0)
                Hout[((size_t)(t - 1) * 2 + d) * 768 + j0 + tid] = hprev;
            if (t + 1 < T_STEPS) {
                const float* gp = Gi + ((size_t)(t + 1) * 2 + d) * G3;
                ngr = gp[        j0 + tid];
                ngz = gp[ 768 + j0 + tid];
                ngn = gp[1536 + j0 + tid];
            }
        }

        const float* hb = hsh[t & 1];
        float4 h4[3];
        #pragma unroll
        for (int i = 0; i < 3; ++i)
            h4[i] = *(const float4*)&hb[i * 256 + lane * 4];

        float S[6];
        #pragma unroll
        for (int m = 0; m < 6; ++m) {
            float s = 0.f;
            s = fmaf(w[m][0].x, h4[0].x, s); s = fmaf(w[m][0].y, h4[0].y, s);
            s = fmaf(w[m][0].z, h4[0].z, s); s = fmaf(w[m][0].w, h4[0].w, s);
            s = fmaf(w[m][1].x, h4[1].x, s); s = fmaf(w[m][1].y, h4[1].y, s);
            s = fmaf(w[m][1].z, h4[1].z, s); s = fmaf(w[m][1].w, h4[1].w, s);
            s = fmaf(w[m][2].x, h4[2].x, s); s = fmaf(w[m][2].y, h4[2].y, s);
            s = fmaf(w[m][2].z, h4[2].z, s); s = fmaf(w[m][2].w, h4[2].w, s);
            S[m] = s;
        }
        #pragma unroll
        for (int sft = 1; sft < 64; sft <<= 1) {
            #pragma unroll
            for (int m = 0; m < 6; ++m) S[m] += __shfl_xor(S[m], sft);
        }
        if (lane < 6) gsum[wave * 6 + lane] = S[lane];
        __syncthreads();

        // --- Phase 3: gates + single-transaction publish (wave 0, tid<8) ---
        if (tid < 8) {
            const int wv = tid & 3, ri = tid >> 2;   // row j0+tid = j0+wv+4*ri
            float Sr = gsum[wv * 6 + 0 + ri];
            float Sz = gsum[wv * 6 + 2 + ri];
            float Sn = gsum[wv * 6 + 4 + ri];
            float r = sigf(gi_r + Sr + bh_r);
            float z = sigf(gi_z + Sz + bh_z);
            float n = tanhf(gi_n + r * (Sn + bh_n));
            float hn = (1.0f - z) * n + z * hprev;
            hprev = hn;
            unsigned long long pair =
                ((unsigned long long)__float_as_uint(hn) << 32)
                | (unsigned long long)(unsigned)(t + 1);
            st_pair(exch + (size_t)(((t & 1) * 2 + d)) * 768 + j0 + tid, pair);
            gi_r = ngr; gi_z = ngz; gi_n = ngn;
        }
        // no third sync: next-step gsum writes are ordered behind wave-0's
        // gate reads by the next step's phase-1/2 barriers; hsh is
        // parity-staggered (R9-proven).
    }
    // flush the last Hout row
    if (tid < 8)
        Hout[((size_t)(T_STEPS - 1) * 2 + d) * 768 + j0 + tid] = hprev;
}

// ---------------------------------------------------------------------------
// Final FC + sigmoid (unchanged)
// ---------------------------------------------------------------------------
__device__ __forceinline__ float dot4(float4 a, float4 b) {
    return a.x * b.x + a.y * b.y + a.z * b.z + a.w * b.w;
}

__global__ __launch_bounds__(64)
void fc_sig(const float* __restrict__ hin, const float* __restrict__ fw,
            const float* __restrict__ fb, float* __restrict__ out) {
    const int lane = threadIdx.x;
    const int row  = blockIdx.x;
    const float* wr = fw + (size_t)row * HC;
    float acc = 0.0f;
    #pragma unroll
    for (int i = 0; i < 6; ++i) {
        float4 w4 = *(const float4*)(wr  + i * 256 + lane * 4);
        float4 h4 = *(const float4*)(hin + i * 256 + lane * 4);
        acc += dot4(w4, h4);
    }
    #pragma unroll
    for (int s = 1; s < 64; s <<= 1) acc += __shfl_xor(acc, s);
    if (lane == 0) out[row] = sigf(acc + fb[row]);
}

// ---------------------------------------------------------------------------
extern "C" void kernel_launch(void* const* d_in, const int* in_sizes, int n_in,
                              void* d_out, int out_size, void* d_ws, size_t ws_size,
                              hipStream_t stream) {
    (void)in_sizes; (void)n_in; (void)out_size; (void)ws_size;

    const float* x     = (const float*)d_in[0];   // [8192,512]
    const float* h0    = (const float*)d_in[1];   // [4,768]
    const float* w_ih0 = (const float*)d_in[2];   // [2,2304,512]
    const float* w_hh0 = (const float*)d_in[3];   // [2,2304,768]
    const float* b_ih0 = (const float*)d_in[4];   // [2,2304]
    const float* b_hh0 = (const float*)d_in[5];
    const float* w_ih1 = (const float*)d_in[6];   // [2,2304,1536]
    const float* w_hh1 = (const float*)d_in[7];
    const float* b_ih1 = (const float*)d_in[8];
    const float* b_hh1 = (const float*)d_in[9];
    const float* fc_w  = (const float*)d_in[10];  // [256,1536]
    const float* fc_b  = (const float*)d_in[11];  // [256]
    float* out = (float*)d_out;

    char* ws = (char*)d_ws;
    // Exchange pair buffers (tags must start 0): 2*2*768*8 B = 24 KiB each.
    unsigned long long* exch0 = (unsigned long long*)(ws + 4096);
    unsigned long long* exch1 = (unsigned long long*)(ws + 4096 + 24576);
    // CAS claim tables, one per recurrence launch (zeroed by the memset).
    unsigned* ownA = (unsigned*)(ws + 57344);
    unsigned* ownB = (unsigned*)(ws + 58368);
    float* Gi    = (float*)(ws + 65536);           // [8192][4608] fp32 = 144 MiB
    size_t gi_bytes = (size_t)T_STEPS * NDR * sizeof(float);
    float* Hout  = (float*)(ws + 65536 + gi_bytes); // [8192][2][768] = 48 MiB

    hipMemsetAsync(ws, 0, 65536, stream);

    dim3 ggrid(NDR / 128, T_STEPS / 128);  // (36, 64)

    // Phase 1: Gi0 = x @ w_ih0^T + b_ih0
    gemm_xwt<<<ggrid, 256, 0, stream>>>(x, w_ih0, b_ih0, Gi, T_STEPS, NDR, 512);
    // Phase 2: layer-0 recurrence, store all h0[t]
    gru_rec<<<CLAIM_GRID, 256, 0, stream>>>(Gi, w_hh0, b_hh0, h0, exch0,
                                            ownA, Hout);
    // Phase 3: Gi1 = concat_h0 @ w_ih1^T + b_ih1
    gemm_xwt<<<ggrid, 256, 0, stream>>>(Hout, w_ih1, b_ih1, Gi, T_STEPS, NDR, HC);
    // Phase 4: layer-1 recurrence
    gru_rec<<<CLAIM_GRID, 256, 0, stream>>>(Gi, w_hh1, b_hh1, h0 + 2 * HDIM,
                                            exch1, ownB, Hout);
    // Phase 5: y = sigmoid(fc_w @ h_last + fc_b)
    fc_sig<<<256, 64, 0, stream>>>(Hout + (size_t)(T_STEPS - 1) * HC,
                                   fc_w, fc_b, out);
}

// Round 4
// 37451.996 us; speedup vs baseline: 1.9550x; 1.9550x over previous
//
#include <hip/hip_runtime.h>
#include <cstdint>

#define T_STEPS 8192
#define HDIM    768
#define G3      2304   // 3*H
#define NDR     4608   // 2*3*H
#define HC      1536   // 2*H
#define GPD     96     // workgroups per direction
#define NWG     192    // 2 dirs x 96 WGs (independent cliques)
#define C_ROWS  8      // h-rows per workgroup (2 per wave)

// ---------------------------------------------------------------------------
// GEMM: C[m][n] = sum_k X[m][k] * W[n][k] + bias[n]  (unchanged)
// ---------------------------------------------------------------------------
__global__ __launch_bounds__(256)
void gemm_xwt(const float* __restrict__ X, const float* __restrict__ W,
              const float* __restrict__ bias, float* __restrict__ C,
              int M, int N, int K) {
    __shared__ float As[16][132];
    __shared__ float Bs[16][132];
    const int tid = threadIdx.x;
    const int m0 = blockIdx.y * 128;
    const int n0 = blockIdx.x * 128;
    const int tm = tid >> 4;
    const int tn = tid & 15;
    float acc[8][8] = {};
    for (int k0 = 0; k0 < K; k0 += 16) {
        #pragma unroll
        for (int l = 0; l < 2; ++l) {
            int idx = l * 256 + tid;
            int row = idx >> 2;
            int kc  = (idx & 3) << 2;
            float4 a = *(const float4*)(X + (size_t)(m0 + row) * K + k0 + kc);
            As[kc + 0][row] = a.x; As[kc + 1][row] = a.y;
            As[kc + 2][row] = a.z; As[kc + 3][row] = a.w;
            float4 b = *(const float4*)(W + (size_t)(n0 + row) * K + k0 + kc);
            Bs[kc + 0][row] = b.x; Bs[kc + 1][row] = b.y;
            Bs[kc + 2][row] = b.z; Bs[kc + 3][row] = b.w;
        }
        __syncthreads();
        #pragma unroll
        for (int k = 0; k < 16; ++k) {
            float4 a0 = *(const float4*)&As[k][tm * 8];
            float4 a1 = *(const float4*)&As[k][tm * 8 + 4];
            float4 b0 = *(const float4*)&Bs[k][tn * 8];
            float4 b1 = *(const float4*)&Bs[k][tn * 8 + 4];
            float av[8] = {a0.x, a0.y, a0.z, a0.w, a1.x, a1.y, a1.z, a1.w};
            float bv[8] = {b0.x, b0.y, b0.z, b0.w, b1.x, b1.y, b1.z, b1.w};
            #pragma unroll
            for (int i = 0; i < 8; ++i)
                #pragma unroll
                for (int j = 0; j < 8; ++j)
                    acc[i][j] = fmaf(av[i], bv[j], acc[i][j]);
        }
        __syncthreads();
    }
    float bfrag[8];
    #pragma unroll
    for (int j = 0; j < 8; ++j) bfrag[j] = bias[n0 + tn * 8 + j];
    #pragma unroll
    for (int i = 0; i < 8; ++i) {
        float* cp = C + (size_t)(m0 + tm * 8 + i) * N + n0 + tn * 8;
        float4 o0, o1;
        o0.x = acc[i][0] + bfrag[0]; o0.y = acc[i][1] + bfrag[1];
        o0.z = acc[i][2] + bfrag[2]; o0.w = acc[i][3] + bfrag[3];
        o1.x = acc[i][4] + bfrag[4]; o1.y = acc[i][5] + bfrag[5];
        o1.z = acc[i][6] + bfrag[6]; o1.w = acc[i][7] + bfrag[7];
        *(float4*)(cp + 0) = o0;
        *(float4*)(cp + 4) = o1;
    }
}

// ---------------------------------------------------------------------------
// GRU recurrence, R13 = R9 (proven) + three verified-safe deltas:
// 1) COALESCED poll (transposed ownership): lane tid owns pairs {tid+96k};
//    a wave-load touches 8 consecutive 64-B lines instead of 64 scattered
//    ones (R9 was stride-64B across lanes = 512 line-requests/WG/retry).
//    Protocol, scope (agent, always coherence-point-fresh) unchanged.
// 2) Gi prefetch for t+1 issued in phase 2 (after the poll), consumed next
//    step: its HBM latency no longer sits under the poll's vmcnt wait.
// 3) Hout(t-1) store deferred to phase 2 (off the publish critical path).
// NO sc0 polls (R12 lesson: weaker-scope polls against sc1 stores are
// eviction-timed, not update-timed). NO claim tables, NO XCC_ID.
// Dot partition / butterfly / gates / publish protocol identical to R9.
// Overwrite-safety (2-deep parity) induction unchanged: a WG passes poll(t)
// only after every WG published tag t, which required their poll(t-1);
// hence no producer can be >1 step ahead of any consumer.
// ---------------------------------------------------------------------------
__device__ __forceinline__ float sigf(float x) {
    return 1.0f / (1.0f + expf(-x));
}
__device__ __forceinline__ unsigned long long ld_pair(
        const unsigned long long* p) {
    return __hip_atomic_load(p, __ATOMIC_RELAXED, __HIP_MEMORY_SCOPE_AGENT);
}
__device__ __forceinline__ void st_pair(unsigned long long* p,
                                        unsigned long long v) {
    __hip_atomic_store(p, v, __ATOMIC_RELAXED, __HIP_MEMORY_SCOPE_AGENT);
}

__global__ __launch_bounds__(256, 1)
void gru_rec(const float* __restrict__ Gi,   // [T][2][2304]
             const float* __restrict__ whh,  // [2][2304][768]
             const float* __restrict__ bhh,  // [2][2304]
             const float* __restrict__ h0,   // [2][768] (layer slice)
             unsigned long long* __restrict__ exch, // [2 par][2 dir][768]
             float* __restrict__ Hout) {     // [T][2][768]
    const int tid  = threadIdx.x;
    const int lane = tid & 63;
    const int wave = tid >> 6;
    const int bid  = blockIdx.x;
    const int d    = bid / GPD;
    const int j0   = (bid % GPD) * C_ROWS;

    __shared__ float hsh[2][768];
    __shared__ float gsum[24];

    // Register-resident weights: m = g*2 + ri, row = j0 + wave + 4*ri.
    float4 w[6][3];
    #pragma unroll
    for (int g = 0; g < 3; ++g)
        #pragma unroll
        for (int ri = 0; ri < 2; ++ri) {
            const float* wrow = whh + (size_t)d * G3 * HDIM
                + (size_t)(g * 768 + j0 + wave + 4 * ri) * HDIM;
            #pragma unroll
            for (int i = 0; i < 3; ++i)
                w[g * 2 + ri][i] = *(const float4*)(wrow + i * 256 + lane * 4);
        }

    // Gate lanes (wave 0, tid<8): row = j0 + tid; constants + initial h + Gi(0).
    float bh_r = 0.f, bh_z = 0.f, bh_n = 0.f, hprev = 0.f;
    float gi_r = 0.f, gi_z = 0.f, gi_n = 0.f;
    if (tid < 8) {
        const int row = j0 + tid;
        bh_r  = bhh[d * G3 +        row];
        bh_z  = bhh[d * G3 +  768 + row];
        bh_n  = bhh[d * G3 + 1536 + row];
        hprev = h0[d * 768 + row];
        const float* gp = Gi + (size_t)d * G3;      // t = 0
        gi_r = gp[        j0 + tid];
        gi_z = gp[ 768 + j0 + tid];
        gi_n = gp[1536 + j0 + tid];
    }

    for (int t = 0; t < T_STEPS; ++t) {
        // --- Phase 1: coalesced poll (96 lanes; lane owns pairs tid+96k) ---
        if (tid < 96) {
            if (t == 0) {
                const float* src = h0 + d * 768;
                #pragma unroll
                for (int k = 0; k < 8; ++k)
                    hsh[0][96 * k + tid] = src[96 * k + tid];
            } else {
                const unsigned long long* src = exch
                    + (size_t)((((t - 1) & 1) * 2 + d)) * 768 + tid;
                unsigned long long v[8];
                bool ok;
                do {
                    #pragma unroll
                    for (int k = 0; k < 8; ++k)
                        v[k] = ld_pair(src + 96 * k);
                    ok = true;
                    #pragma unroll
                    for (int k = 0; k < 8; ++k)
                        ok &= ((unsigned)v[k] >= (unsigned)t);
                } while (!ok);
                #pragma unroll
                for (int k = 0; k < 8; ++k)
                    hsh[t & 1][96 * k + tid] =
                        __uint_as_float((unsigned)(v[k] >> 32));
            }
        }
        __syncthreads();

        // --- Phase 2: deferred Hout(t-1), Gi prefetch(t+1), dot+butterfly ---
        float ngr = 0.f, ngz = 0.f, ngn = 0.f;
        if (tid < 8) {
            if (t > 0)
                Hout[((size_t)(t - 1) * 2 + d) * 768 + j0 + tid] = hprev;
            if (t + 1 < T_STEPS) {
                const float* gp = Gi + ((size_t)(t + 1) * 2 + d) * G3;
                ngr = gp[        j0 + tid];
                ngz = gp[ 768 + j0 + tid];
                ngn = gp[1536 + j0 + tid];
            }
        }

        const float* hb = hsh[t & 1];
        float4 h4[3];
        #pragma unroll
        for (int i = 0; i < 3; ++i)
            h4[i] = *(const float4*)&hb[i * 256 + lane * 4];

        float S[6];
        #pragma unroll
        for (int m = 0; m < 6; ++m) {
            float s = 0.f;
            s = fmaf(w[m][0].x, h4[0].x, s); s = fmaf(w[m][0].y, h4[0].y, s);
            s = fmaf(w[m][0].z, h4[0].z, s); s = fmaf(w[m][0].w, h4[0].w, s);
            s = fmaf(w[m][1].x, h4[1].x, s); s = fmaf(w[m][1].y, h4[1].y, s);
            s = fmaf(w[m][1].z, h4[1].z, s); s = fmaf(w[m][1].w, h4[1].w, s);
            s = fmaf(w[m][2].x, h4[2].x, s); s = fmaf(w[m][2].y, h4[2].y, s);
            s = fmaf(w[m][2].z, h4[2].z, s); s = fmaf(w[m][2].w, h4[2].w, s);
            S[m] = s;
        }
        #pragma unroll
        for (int sft = 1; sft < 64; sft <<= 1) {
            #pragma unroll
            for (int m = 0; m < 6; ++m) S[m] += __shfl_xor(S[m], sft);
        }
        if (lane < 6) gsum[wave * 6 + lane] = S[lane];
        __syncthreads();

        // --- Phase 3: gates + single-transaction publish (wave 0, tid<8) ---
        if (tid < 8) {
            const int wv = tid & 3, ri = tid >> 2;   // row j0+tid = j0+wv+4*ri
            float Sr = gsum[wv * 6 + 0 + ri];
            float Sz = gsum[wv * 6 + 2 + ri];
            float Sn = gsum[wv * 6 + 4 + ri];
            float r = sigf(gi_r + Sr + bh_r);
            float z = sigf(gi_z + Sz + bh_z);
            float n = tanhf(gi_n + r * (Sn + bh_n));
            float hn = (1.0f - z) * n + z * hprev;
            hprev = hn;
            unsigned long long pair =
                ((unsigned long long)__float_as_uint(hn) << 32)
                | (unsigned long long)(unsigned)(t + 1);
            st_pair(exch + (size_t)(((t & 1) * 2 + d)) * 768 + j0 + tid, pair);
            gi_r = ngr; gi_z = ngz; gi_n = ngn;
        }
        // no third sync: next-step gsum writes are ordered behind wave-0's
        // gate reads by the next step's phase-1/2 barriers; hsh is
        // parity-staggered (R9-proven).
    }
    // flush the last Hout row
    if (tid < 8)
        Hout[((size_t)(T_STEPS - 1) * 2 + d) * 768 + j0 + tid] = hprev;
}

// ---------------------------------------------------------------------------
// Final FC + sigmoid (unchanged)
// ---------------------------------------------------------------------------
__device__ __forceinline__ float dot4(float4 a, float4 b) {
    return a.x * b.x + a.y * b.y + a.z * b.z + a.w * b.w;
}

__global__ __launch_bounds__(64)
void fc_sig(const float* __restrict__ hin, const float* __restrict__ fw,
            const float* __restrict__ fb, float* __restrict__ out) {
    const int lane = threadIdx.x;
    const int row  = blockIdx.x;
    const float* wr = fw + (size_t)row * HC;
    float acc = 0.0f;
    #pragma unroll
    for (int i = 0; i < 6; ++i) {
        float4 w4 = *(const float4*)(wr  + i * 256 + lane * 4);
        float4 h4 = *(const float4*)(hin + i * 256 + lane * 4);
        acc += dot4(w4, h4);
    }
    #pragma unroll
    for (int s = 1; s < 64; s <<= 1) acc += __shfl_xor(acc, s);
    if (lane == 0) out[row] = sigf(acc + fb[row]);
}

// ---------------------------------------------------------------------------
extern "C" void kernel_launch(void* const* d_in, const int* in_sizes, int n_in,
                              void* d_out, int out_size, void* d_ws, size_t ws_size,
                              hipStream_t stream) {
    (void)in_sizes; (void)n_in; (void)out_size; (void)ws_size;

    const float* x     = (const float*)d_in[0];   // [8192,512]
    const float* h0    = (const float*)d_in[1];   // [4,768]
    const float* w_ih0 = (const float*)d_in[2];   // [2,2304,512]
    const float* w_hh0 = (const float*)d_in[3];   // [2,2304,768]
    const float* b_ih0 = (const float*)d_in[4];   // [2,2304]
    const float* b_hh0 = (const float*)d_in[5];
    const float* w_ih1 = (const float*)d_in[6];   // [2,2304,1536]
    const float* w_hh1 = (const float*)d_in[7];
    const float* b_ih1 = (const float*)d_in[8];
    const float* b_hh1 = (const float*)d_in[9];
    const float* fc_w  = (const float*)d_in[10];  // [256,1536]
    const float* fc_b  = (const float*)d_in[11];  // [256]
    float* out = (float*)d_out;

    char* ws = (char*)d_ws;
    // Exchange pair buffers (tags must start 0): 2*2*768*8 B = 24 KiB each.
    unsigned long long* exch0 = (unsigned long long*)(ws + 4096);
    unsigned long long* exch1 = (unsigned long long*)(ws + 4096 + 24576);
    float* Gi    = (float*)(ws + 65536);           // [8192][4608] fp32 = 144 MiB
    size_t gi_bytes = (size_t)T_STEPS * NDR * sizeof(float);
    float* Hout  = (float*)(ws + 65536 + gi_bytes); // [8192][2][768] = 48 MiB

    hipMemsetAsync(ws, 0, 65536, stream);

    dim3 ggrid(NDR / 128, T_STEPS / 128);  // (36, 64)

    // Phase 1: Gi0 = x @ w_ih0^T + b_ih0
    gemm_xwt<<<ggrid, 256, 0, stream>>>(x, w_ih0, b_ih0, Gi, T_STEPS, NDR, 512);
    // Phase 2: layer-0 recurrence, store all h0[t]
    gru_rec<<<NWG, 256, 0, stream>>>(Gi, w_hh0, b_hh0, h0, exch0, Hout);
    // Phase 3: Gi1 = concat_h0 @ w_ih1^T + b_ih1
    gemm_xwt<<<ggrid, 256, 0, stream>>>(Hout, w_ih1, b_ih1, Gi, T_STEPS, NDR, HC);
    // Phase 4: layer-1 recurrence
    gru_rec<<<NWG, 256, 0, stream>>>(Gi, w_hh1, b_hh1, h0 + 2 * HDIM, exch1, Hout);
    // Phase 5: y = sigmoid(fc_w @ h_last + fc_b)
    fc_sig<<<256, 64, 0, stream>>>(Hout + (size_t)(T_STEPS - 1) * HC,
                                   fc_w, fc_b, out);
}